// Round 5
// baseline (785.996 us; speedup 1.0000x reference)
//
#include <hip/hip_runtime.h>

// MoE top-2/8: routed bf16-MFMA grouped GEMMs.
// R5: gemm2 K-split x4 (fixes 1-block/CU round quantization: 264 blocks -> 2
// full rounds was 2x ideal); vectorized transpose-convert (float4 -> LDS
// ushort[64][68] -> ushort4 stores). gemm1 schedule untouched.

#define N_TOK 8192
#define DIM   1024
#define HID   2048
#define NEXP  8
#define NK    (N_TOK * 2)
#define MAXT2 72    // max 256-row tiles over all experts (64 full + 8 partial)

typedef __attribute__((ext_vector_type(8))) short short8;
typedef __attribute__((ext_vector_type(4))) float f32x4;

#define BARX() __builtin_amdgcn_s_barrier()
#define FEN()  asm volatile("" ::: "memory")
#define VMW4() asm volatile("s_waitcnt vmcnt(4)" ::: "memory")
#define VMW0() asm volatile("s_waitcnt vmcnt(0)" ::: "memory")
#define PRIO(p) __builtin_amdgcn_s_setprio(p)

static __device__ __forceinline__ unsigned short f2bf(float f) {
  unsigned int u = __float_as_uint(f);
  u += 0x7fffu + ((u >> 16) & 1u);
  return (unsigned short)(u >> 16);
}

static __device__ __forceinline__ void glds16(const void* g, void* l) {
  __builtin_amdgcn_global_load_lds(
      (const __attribute__((address_space(1))) unsigned int*)g,
      (__attribute__((address_space(3))) unsigned int*)l, 16, 0, 0);
}

// ---- convert x (fp32) -> bf16, vectorized ----
__global__ __launch_bounds__(256) void cvt_x_k(const float4* __restrict__ src,
                                               ushort4* __restrict__ dst, int n4) {
  int i = blockIdx.x * 256 + threadIdx.x;
  if (i >= n4) return;
  float4 v = src[i];
  ushort4 o;
  o.x = f2bf(v.x); o.y = f2bf(v.y); o.z = f2bf(v.z); o.w = f2bf(v.w);
  dst[i] = o;
}

// ---- transpose-convert v2: src [E][R][C] fp32 -> dst [E][C][R] bf16 ----
// 64x64 tile; float4 coalesced loads, transposed LDS scatter (2B writes,
// ~4-way), conflict-free ushort4 LDS reads, coalesced ushort4 global stores.
__global__ __launch_bounds__(256) void transpose_cvt_k(const float* __restrict__ src,
                                                       unsigned short* __restrict__ dst,
                                                       int R, int C) {
  __shared__ unsigned short tT[64][68];   // [col][row]; stride 68 -> b64-aligned reads
  const float* s = src + (size_t)blockIdx.z * R * C;
  unsigned short* d = dst + (size_t)blockIdx.z * R * C;
  int c0 = blockIdx.x * 64, r0 = blockIdx.y * 64;
  int tid = threadIdx.x;
#pragma unroll
  for (int it = 0; it < 4; ++it) {
    int idx = it * 256 + tid;
    int rr = idx >> 4;              // 0..63 source row
    int c4 = (idx & 15) * 4;        // 0..60 source col group
    float4 v = *(const float4*)(s + (size_t)(r0 + rr) * C + c0 + c4);
    tT[c4 + 0][rr] = f2bf(v.x);
    tT[c4 + 1][rr] = f2bf(v.y);
    tT[c4 + 2][rr] = f2bf(v.z);
    tT[c4 + 3][rr] = f2bf(v.w);
  }
  __syncthreads();
#pragma unroll
  for (int it = 0; it < 4; ++it) {
    int idx = it * 256 + tid;
    int c = idx >> 4;               // 0..63 dst row (= src col)
    int r4 = (idx & 15) * 4;        // 0..60 dst col group (= src row)
    *(ushort4*)(d + (size_t)(c0 + c) * R + r0 + r4) = *(const ushort4*)&tT[c][r4];
  }
}

// ---- router: fp32 logits, top-2, softmax gates, per-expert counts ----
__global__ __launch_bounds__(256) void router_k(const float* __restrict__ x,
                                                const float* __restrict__ Wr,
                                                int* __restrict__ te, float* __restrict__ tg,
                                                int* __restrict__ cnt) {
  int n = blockIdx.x * 4 + (threadIdx.x >> 6);
  int lane = threadIdx.x & 63;
  float z[8];
#pragma unroll
  for (int e = 0; e < 8; ++e) z[e] = 0.f;
  const float* xr = x + (size_t)n * DIM;
#pragma unroll 4
  for (int i = 0; i < DIM / 64; ++i) {
    int d = lane + i * 64;
    float xv = xr[d];
    float4 w0 = *(const float4*)(Wr + (size_t)d * 8);
    float4 w1 = *(const float4*)(Wr + (size_t)d * 8 + 4);
    z[0] += xv * w0.x; z[1] += xv * w0.y; z[2] += xv * w0.z; z[3] += xv * w0.w;
    z[4] += xv * w1.x; z[5] += xv * w1.y; z[6] += xv * w1.z; z[7] += xv * w1.w;
  }
  for (int off = 32; off; off >>= 1)
#pragma unroll
    for (int e = 0; e < 8; ++e) z[e] += __shfl_down(z[e], off);
  if (lane == 0) {
    int e0 = 0; float v0 = z[0];
#pragma unroll
    for (int e = 1; e < 8; ++e) if (z[e] > v0) { v0 = z[e]; e0 = e; }
    int e1 = -1; float v1 = -3.4e38f;
#pragma unroll
    for (int e = 0; e < 8; ++e) if (e != e0 && z[e] > v1) { v1 = z[e]; e1 = e; }
    float r = expf(v1 - v0);
    float s0 = 1.f / (1.f + r);
    te[n * 2] = e0; te[n * 2 + 1] = e1;
    tg[n * 2] = s0; tg[n * 2 + 1] = r * s0;
    atomicAdd(&cnt[e0], 1);
    atomicAdd(&cnt[e1], 1);
  }
}

// ---- scan: offsets, cursors, 256-row tile offsets ----
__global__ void scan_k(const int* __restrict__ cnt, int* __restrict__ offs,
                       int* __restrict__ cur, int* __restrict__ tl) {
  if (threadIdx.x == 0) {
    int o = 0, t = 0;
    offs[0] = 0; tl[0] = 0;
    for (int e = 0; e < NEXP; ++e) {
      cur[e] = o;
      o += cnt[e];
      offs[e + 1] = o;
      t += (cnt[e] + 255) >> 8;
      tl[e + 1] = t;
    }
  }
}

// ---- scatter tokens into per-expert lists ----
__global__ __launch_bounds__(256) void scatter_k(const int* __restrict__ te,
                                                 const float* __restrict__ tg,
                                                 int* __restrict__ cur,
                                                 int* __restrict__ rows,
                                                 float* __restrict__ rowg) {
  int n = blockIdx.x * 256 + threadIdx.x;
  if (n >= N_TOK) return;
#pragma unroll
  for (int k = 0; k < 2; ++k) {
    int e = te[n * 2 + k];
    int pos = atomicAdd(&cur[e], 1);
    rows[pos] = n;
    rowg[pos] = tg[n * 2 + k];
  }
}

// ================= 8-phase 256x256 grouped GEMM (per-phase interleave) ======
// KSPL: K-split factor (blockIdx.z picks K segment; partial sums accumulate
// via the epilogue's atomicAdd; bias applied only by z==0). GID0 must use
// KSPL=1 (swiGLU needs the full-K sum before the nonlinearity).
template <int GID, int KSPL>
__global__ __launch_bounds__(512, 2) void moe_gemm8p(
    const unsigned short* __restrict__ Asrc,   // xb or hb
    const unsigned short* __restrict__ Wt,     // w1t [E][4096][1024] or w2t [E][1024][2048]
    const float* __restrict__ bias,            // b1 [E][4096] or b2 [E][1024]
    unsigned short* __restrict__ hb,           // GID0 output
    float* __restrict__ out,                   // GID1 output
    const int* __restrict__ rows,
    const float* __restrict__ rowg,
    const int* __restrict__ offs,
    const int* __restrict__ tl) {
  constexpr int KD = (GID == 0) ? DIM : HID;
  constexpr int NT = KD / 64 / KSPL;           // K-tiles per block
  // slabs (elements): A-even 0, A-odd 16384, B-even 32768, B-odd 49152
  __shared__ unsigned short smem[4 * 16384];

  int bt = blockIdx.x;
  if (bt >= tl[NEXP]) return;
  int e = 0;
  while (e < NEXP - 1 && bt >= tl[e + 1]) ++e;
  int rt = bt - tl[e];
  int base = offs[e];
  int cntE = offs[e + 1] - base;
  int row0 = rt * 256;
  int koff = (KSPL > 1) ? (int)blockIdx.z * (KD / KSPL) : 0;

  int tid = threadIdx.x, lane = tid & 63, w = tid >> 6;
  int wr = w >> 2, wc = w & 3;

  // ---------- staging sources/dsts: 2 halves x 2 slots, 2 glds each ----------
  int g8 = (((lane & 7) ^ ((lane >> 3) & 7)) * 8);  // pre-swizzled k-group
  const unsigned short* aP[2][2];
  const unsigned short* bP[2][2];
  int aD[2][2], bD[2][2];
#pragma unroll
  for (int hf = 0; hf < 2; ++hf)
#pragma unroll
    for (int s = 0; s < 2; ++s) {
      int q0 = w * 16 + s * 8;
      // A half hf covers rows with bit6==hf: {0-63,128-191} or {64-127,192-255}
      int rbA = hf == 0 ? (q0 < 64 ? q0 : q0 + 64) : (q0 < 64 ? q0 + 64 : q0 + 128);
      int rA = rbA + (lane >> 3);
      int rr = row0 + rA; rr = rr < cntE ? rr : cntE - 1;
      if (GID == 0) {
        int tok = rows[base + rr];
        aP[hf][s] = Asrc + (size_t)tok * DIM + g8 + koff;
      } else {
        aP[hf][s] = Asrc + (size_t)(base + rr) * HID + g8 + koff;
      }
      aD[hf][s] = rbA * 64;
      int rB = hf * 128 + q0 + (lane >> 3);
      if (GID == 0) {
        int j0h = blockIdx.y * 128;
        int hcol = j0h + (rB >> 5) * 16 + (rB & 15);
        int w1row = hcol + ((rB >> 4) & 1) * HID;   // +HID for b-half of swiGLU
        bP[hf][s] = Wt + ((size_t)e * 2 * HID + w1row) * DIM + g8 + koff;
      } else {
        int j0 = blockIdx.y * 256;
        bP[hf][s] = Wt + ((size_t)e * DIM + (j0 + rB)) * HID + g8 + koff;
      }
      bD[hf][s] = (hf * 128 + q0) * 64;
    }

  auto stA = [&](int t, int hf) {
    if (t < NT) {
#pragma unroll
      for (int s = 0; s < 2; ++s)
        glds16(aP[hf][s] + (size_t)t * 64, smem + (t & 1) * 16384 + aD[hf][s]);
    }
  };
  auto stB = [&](int t, int hf) {
    if (t < NT) {
#pragma unroll
      for (int s = 0; s < 2; ++s)
        glds16(bP[hf][s] + (size_t)t * 64, smem + 32768 + (t & 1) * 16384 + bD[hf][s]);
    }
  };

  // ---------- ds_read offsets (elements), swizzle matches staging ----------
  int arow = wr * 128 + (lane & 15);
  int brow = wc * 64 + (lane & 15);
  int kg = lane >> 4, sx = lane & 7;
  unsigned aoffs[2] = {(unsigned)(arow * 64 + ((kg ^ sx) * 8)),
                       (unsigned)(arow * 64 + (((4 + kg) ^ sx) * 8))};
  unsigned boffs[2] = {(unsigned)(brow * 64 + ((kg ^ sx) * 8)),
                       (unsigned)(brow * 64 + (((4 + kg) ^ sx) * 8))};

  f32x4 acc[8][4];
#pragma unroll
  for (int m = 0; m < 8; ++m)
#pragma unroll
    for (int n = 0; n < 4; ++n) acc[m][n] = (f32x4){0.f, 0.f, 0.f, 0.f};

  short8 a[2][4], b[2][4];

#define MFMA_Q(MB, NB)                                                        \
  PRIO(1);                                                                    \
  _Pragma("unroll") for (int ks = 0; ks < 2; ++ks)                            \
  _Pragma("unroll") for (int m = 0; m < 4; ++m)                               \
  _Pragma("unroll") for (int n = 0; n < 2; ++n)                               \
    acc[(MB) + m][(NB) + n] = __builtin_amdgcn_mfma_f32_16x16x32_bf16(        \
        a[ks][m], b[ks][(NB) + n], acc[(MB) + m][(NB) + n], 0, 0, 0);         \
  PRIO(0)

  // ---------- prologue: A0, B0, A1 halves; land A0,B0 ----------
  stA(0, 0); stA(0, 1); stB(0, 0); stB(0, 1); stA(1, 0); stA(1, 1);
  VMW4(); FEN(); BARX(); FEN();

  for (int it = 0; it < NT / 2; ++it) {
    int T = 2 * it;
    bool notlast = (it < NT / 2 - 1);
#pragma unroll
    for (int half = 0; half < 2; ++half) {
      unsigned Ab = half ? 16384u : 0u;
      unsigned Bb = 32768u + Ab;
      int Tn = T + half;
      // ---- P0/P4: a[h0], b[v0]; stage B(Tn+1).h0 ----
#pragma unroll
      for (int ks = 0; ks < 2; ++ks) {
#pragma unroll
        for (int m = 0; m < 4; ++m)
          a[ks][m] = *(const short8*)(smem + Ab + aoffs[ks] + m * 1024);
#pragma unroll
        for (int n = 0; n < 2; ++n)
          b[ks][n] = *(const short8*)(smem + Bb + boffs[ks] + n * 1024);
      }
      stB(Tn + 1, 0);
      FEN(); BARX(); FEN();
      MFMA_Q(0, 0);
      FEN(); BARX(); FEN();
      // ---- P1/P5: b[v1]; stage B(Tn+1).h1 ----
#pragma unroll
      for (int ks = 0; ks < 2; ++ks)
#pragma unroll
        for (int n = 2; n < 4; ++n)
          b[ks][n] = *(const short8*)(smem + Bb + boffs[ks] + n * 1024);
      stB(Tn + 1, 1);
      FEN(); BARX(); FEN();
      MFMA_Q(0, 2);
      FEN(); BARX(); FEN();
      // ---- P2/P6: a[h1]; stage A(Tn+2).q0 ----
#pragma unroll
      for (int ks = 0; ks < 2; ++ks)
#pragma unroll
        for (int m = 0; m < 4; ++m)
          a[ks][m] = *(const short8*)(smem + Ab + aoffs[ks] + (4 + m) * 1024);
      stA(Tn + 2, 0);
      FEN(); BARX(); FEN();
      MFMA_Q(4, 2);
      FEN(); BARX(); FEN();
      // ---- P3/P7: stage A(Tn+2).q1; MFMA; guard-before-barrier ----
      stA(Tn + 2, 1);
      FEN(); BARX(); FEN();
      MFMA_Q(4, 0);
      if (half == 0) {
        if (notlast) { VMW4(); } else { VMW0(); }
      } else {
        VMW4();
      }
      FEN(); BARX(); FEN();
    }
  }
#undef MFMA_Q

  // ---------- epilogue ----------
  int rowl = lane >> 4, coll = lane & 15;
  if (GID == 0) {
    int j0h = blockIdx.y * 128;
#pragma unroll
    for (int pair = 0; pair < 2; ++pair) {
      int hcol = j0h + (2 * wc + pair) * 16 + coll;
      float ba = bias[e * 2 * HID + hcol];
      float bb = bias[e * 2 * HID + HID + hcol];
#pragma unroll
      for (int m = 0; m < 8; ++m)
#pragma unroll
        for (int j = 0; j < 4; ++j) {
          int grow = row0 + wr * 128 + m * 16 + rowl * 4 + j;
          if (grow < cntE) {
            float av = acc[m][2 * pair][j] + ba;
            float bv = acc[m][2 * pair + 1][j] + bb;
            float hv = av / (1.f + __expf(-av)) * bv;
            hb[(size_t)(base + grow) * HID + hcol] = f2bf(hv);
          }
        }
    }
  } else {
    int j0 = blockIdx.y * 256;
    bool addb = (KSPL == 1) || (blockIdx.z == 0);
    float bv[4];
#pragma unroll
    for (int n = 0; n < 4; ++n)
      bv[n] = addb ? bias[e * DIM + j0 + wc * 64 + n * 16 + coll] : 0.f;
#pragma unroll
    for (int m = 0; m < 8; ++m)
#pragma unroll
      for (int j = 0; j < 4; ++j) {
        int grow = row0 + wr * 128 + m * 16 + rowl * 4 + j;
        if (grow < cntE) {
          int tok = rows[base + grow];
          float g = rowg[base + grow];
#pragma unroll
          for (int n = 0; n < 4; ++n) {
            int col = j0 + wc * 64 + n * 16 + coll;
            atomicAdd(&out[(size_t)tok * DIM + col], g * (acc[m][n][j] + bv[n]));
          }
        }
      }
  }
}

extern "C" void kernel_launch(void* const* d_in, const int* in_sizes, int n_in,
                              void* d_out, int out_size, void* d_ws, size_t ws_size,
                              hipStream_t stream) {
  (void)in_sizes; (void)n_in; (void)out_size;
  const float* x  = (const float*)d_in[0];
  const float* Wr = (const float*)d_in[1];
  const float* W1 = (const float*)d_in[2];
  const float* b1 = (const float*)d_in[3];
  const float* W2 = (const float*)d_in[4];
  const float* b2 = (const float*)d_in[5];
  float* out = (float*)d_out;
  char* ws = (char*)d_ws;

  const size_t o_xb   = 0;
  const size_t o_w1t  = o_xb   + (size_t)N_TOK * DIM * 2;
  const size_t o_w2t  = o_w1t  + (size_t)NEXP * 2 * HID * DIM * 2;
  const size_t o_hb   = o_w2t  + (size_t)NEXP * DIM * HID * 2;
  const size_t o_rows = o_hb   + (size_t)NK * HID * 2;
  const size_t o_rowg = o_rows + (size_t)NK * 4;
  const size_t o_te   = o_rowg + (size_t)NK * 4;
  const size_t o_tg   = o_te   + (size_t)NK * 4;
  const size_t o_cnt  = o_tg   + (size_t)NK * 4;
  const size_t o_offs = o_cnt  + 64;
  const size_t o_cur  = o_offs + 64;
  const size_t o_t1   = o_cur  + 64;
  const size_t need   = o_t1   + 64;
  if (ws_size < need) return;

  unsigned short* xb  = (unsigned short*)(ws + o_xb);
  unsigned short* w1t = (unsigned short*)(ws + o_w1t);
  unsigned short* w2t = (unsigned short*)(ws + o_w2t);
  unsigned short* hb  = (unsigned short*)(ws + o_hb);
  int*   rows = (int*)(ws + o_rows);
  float* rowg = (float*)(ws + o_rowg);
  int*   te   = (int*)(ws + o_te);
  float* tg   = (float*)(ws + o_tg);
  int*   cnt  = (int*)(ws + o_cnt);
  int*   offs = (int*)(ws + o_offs);
  int*   cur  = (int*)(ws + o_cur);
  int*   tl   = (int*)(ws + o_t1);

  hipMemsetAsync(out, 0, (size_t)N_TOK * DIM * sizeof(float), stream);
  hipMemsetAsync(cnt, 0, NEXP * sizeof(int), stream);

  cvt_x_k<<<(N_TOK * DIM / 4 + 255) / 256, 256, 0, stream>>>(
      (const float4*)x, (ushort4*)xb, N_TOK * DIM / 4);
  transpose_cvt_k<<<dim3(2 * HID / 64, DIM / 64, NEXP), 256, 0, stream>>>(W1, w1t, DIM, 2 * HID);
  transpose_cvt_k<<<dim3(DIM / 64, HID / 64, NEXP), 256, 0, stream>>>(W2, w2t, HID, DIM);
  router_k<<<N_TOK / 4, 256, 0, stream>>>(x, Wr, te, tg, cnt);
  scan_k<<<1, 64, 0, stream>>>(cnt, offs, cur, tl);
  scatter_k<<<N_TOK / 256, 256, 0, stream>>>(te, tg, cur, rows, rowg);
  moe_gemm8p<0, 1><<<dim3(MAXT2, HID / 128), 512, 0, stream>>>(
      xb, w1t, b1, hb, nullptr, rows, rowg, offs, tl);
  moe_gemm8p<1, 4><<<dim3(MAXT2, DIM / 256, 4), 512, 0, stream>>>(
      hb, w2t, b2, nullptr, out, rows, rowg, offs, tl);
}

// Round 6
// 672.415 us; speedup vs baseline: 1.1689x; 1.1689x over previous
//
#include <hip/hip_runtime.h>

// MoE top-2/8: routed bf16-MFMA grouped GEMMs.
// R6: revert gemm2 K-split (atomic RMW blowup); fast transpose v3 (8B LDS
// writes, coalesced ushort4 stores); XCD chunked swizzle on both GEMM grids;
// cvt_x fused into router.

#define N_TOK 8192
#define DIM   1024
#define HID   2048
#define NEXP  8
#define NK    (N_TOK * 2)
#define MAXT2 72    // max 256-row tiles over all experts (64 full + 8 partial)

typedef __attribute__((ext_vector_type(8))) short short8;
typedef __attribute__((ext_vector_type(4))) float f32x4;

#define BARX() __builtin_amdgcn_s_barrier()
#define FEN()  asm volatile("" ::: "memory")
#define VMW4() asm volatile("s_waitcnt vmcnt(4)" ::: "memory")
#define VMW0() asm volatile("s_waitcnt vmcnt(0)" ::: "memory")
#define PRIO(p) __builtin_amdgcn_s_setprio(p)

static __device__ __forceinline__ unsigned short f2bf(float f) {
  unsigned int u = __float_as_uint(f);
  u += 0x7fffu + ((u >> 16) & 1u);
  return (unsigned short)(u >> 16);
}

static __device__ __forceinline__ void glds16(const void* g, void* l) {
  __builtin_amdgcn_global_load_lds(
      (const __attribute__((address_space(1))) unsigned int*)g,
      (__attribute__((address_space(3))) unsigned int*)l, 16, 0, 0);
}

// ---- transpose-convert v3: src [E][R][C] fp32 -> dst [E][C][R] bf16 ----
// Each thread loads a 4-row column quad (scalar f32, coalesced across lanes),
// packs to ushort4, one 8B LDS write into transposed layout; reads are
// ushort4 + coalesced 8B global stores. HBM-bound by design.
__global__ __launch_bounds__(256) void transpose_cvt_k(const float* __restrict__ src,
                                                       unsigned short* __restrict__ dst,
                                                       int R, int C) {
  __shared__ unsigned short tT[64][68];   // [col][row], stride 68 (8B aligned)
  const float* s = src + (size_t)blockIdx.z * R * C;
  unsigned short* d = dst + (size_t)blockIdx.z * R * C;
  int c0 = blockIdx.x * 64, r0 = blockIdx.y * 64;
  int tid = threadIdx.x;
  int c = tid & 63;           // source col for this thread
  int rq = tid >> 6;          // wave id 0..3
#pragma unroll
  for (int q = 0; q < 4; ++q) {
    int rb = q * 16 + rq * 4;
    ushort4 v;
    v.x = f2bf(s[(size_t)(r0 + rb + 0) * C + c0 + c]);
    v.y = f2bf(s[(size_t)(r0 + rb + 1) * C + c0 + c]);
    v.z = f2bf(s[(size_t)(r0 + rb + 2) * C + c0 + c]);
    v.w = f2bf(s[(size_t)(r0 + rb + 3) * C + c0 + c]);
    *(ushort4*)&tT[c][rb] = v;
  }
  __syncthreads();
#pragma unroll
  for (int it = 0; it < 4; ++it) {
    int idx = it * 256 + tid;
    int cc = idx >> 4;              // dst row (= src col)
    int r4 = (idx & 15) * 4;        // dst col group (= src row)
    *(ushort4*)(d + (size_t)(c0 + cc) * R + r0 + r4) = *(const ushort4*)&tT[cc][r4];
  }
}

// ---- router + x->bf16 convert fused ----
__global__ __launch_bounds__(256) void router_k(const float* __restrict__ x,
                                                const float* __restrict__ Wr,
                                                unsigned short* __restrict__ xb,
                                                int* __restrict__ te, float* __restrict__ tg,
                                                int* __restrict__ cnt) {
  int n = blockIdx.x * 4 + (threadIdx.x >> 6);
  int lane = threadIdx.x & 63;
  float z[8];
#pragma unroll
  for (int e = 0; e < 8; ++e) z[e] = 0.f;
  const float* xr = x + (size_t)n * DIM;
  unsigned short* xbr = xb + (size_t)n * DIM;
#pragma unroll 4
  for (int i = 0; i < DIM / 64; ++i) {
    int d = lane + i * 64;
    float xv = xr[d];
    xbr[d] = f2bf(xv);
    float4 w0 = *(const float4*)(Wr + (size_t)d * 8);
    float4 w1 = *(const float4*)(Wr + (size_t)d * 8 + 4);
    z[0] += xv * w0.x; z[1] += xv * w0.y; z[2] += xv * w0.z; z[3] += xv * w0.w;
    z[4] += xv * w1.x; z[5] += xv * w1.y; z[6] += xv * w1.z; z[7] += xv * w1.w;
  }
  for (int off = 32; off; off >>= 1)
#pragma unroll
    for (int e = 0; e < 8; ++e) z[e] += __shfl_down(z[e], off);
  if (lane == 0) {
    int e0 = 0; float v0 = z[0];
#pragma unroll
    for (int e = 1; e < 8; ++e) if (z[e] > v0) { v0 = z[e]; e0 = e; }
    int e1 = -1; float v1 = -3.4e38f;
#pragma unroll
    for (int e = 0; e < 8; ++e) if (e != e0 && z[e] > v1) { v1 = z[e]; e1 = e; }
    float r = expf(v1 - v0);
    float s0 = 1.f / (1.f + r);
    te[n * 2] = e0; te[n * 2 + 1] = e1;
    tg[n * 2] = s0; tg[n * 2 + 1] = r * s0;
    atomicAdd(&cnt[e0], 1);
    atomicAdd(&cnt[e1], 1);
  }
}

// ---- scan: offsets, cursors, 256-row tile offsets ----
__global__ void scan_k(const int* __restrict__ cnt, int* __restrict__ offs,
                       int* __restrict__ cur, int* __restrict__ tl) {
  if (threadIdx.x == 0) {
    int o = 0, t = 0;
    offs[0] = 0; tl[0] = 0;
    for (int e = 0; e < NEXP; ++e) {
      cur[e] = o;
      o += cnt[e];
      offs[e + 1] = o;
      t += (cnt[e] + 255) >> 8;
      tl[e + 1] = t;
    }
  }
}

// ---- scatter tokens into per-expert lists ----
__global__ __launch_bounds__(256) void scatter_k(const int* __restrict__ te,
                                                 const float* __restrict__ tg,
                                                 int* __restrict__ cur,
                                                 int* __restrict__ rows,
                                                 float* __restrict__ rowg) {
  int n = blockIdx.x * 256 + threadIdx.x;
  if (n >= N_TOK) return;
#pragma unroll
  for (int k = 0; k < 2; ++k) {
    int e = te[n * 2 + k];
    int pos = atomicAdd(&cur[e], 1);
    rows[pos] = n;
    rowg[pos] = tg[n * 2 + k];
  }
}

// ================= 8-phase 256x256 grouped GEMM (per-phase interleave) ======
template <int GID>
__global__ __launch_bounds__(512, 2) void moe_gemm8p(
    const unsigned short* __restrict__ Asrc,   // xb or hb
    const unsigned short* __restrict__ Wt,     // w1t [E][4096][1024] or w2t [E][1024][2048]
    const float* __restrict__ bias,            // b1 [E][4096] or b2 [E][1024]
    unsigned short* __restrict__ hb,           // GID0 output
    float* __restrict__ out,                   // GID1 output
    const int* __restrict__ rows,
    const float* __restrict__ rowg,
    const int* __restrict__ offs,
    const int* __restrict__ tl) {
  constexpr int KD = (GID == 0) ? DIM : HID;
  constexpr int NT = KD / 64;
  // slabs (elements): A-even 0, A-odd 16384, B-even 32768, B-odd 49152
  __shared__ unsigned short smem[4 * 16384];

  // XCD chunked swizzle: physical id p -> logical l so XCD k (= p%8) gets a
  // contiguous logical range. grid sizes (72*16, 72*4) are both %8==0.
  int gx = gridDim.x;
  int flat = blockIdx.y * gx + blockIdx.x;
  int q8 = (gx * gridDim.y) >> 3;
  flat = (flat & 7) * q8 + (flat >> 3);
  int bt = flat % gx;
  int jb = flat / gx;

  if (bt >= tl[NEXP]) return;
  int e = 0;
  while (e < NEXP - 1 && bt >= tl[e + 1]) ++e;
  int rt = bt - tl[e];
  int base = offs[e];
  int cntE = offs[e + 1] - base;
  int row0 = rt * 256;

  int tid = threadIdx.x, lane = tid & 63, w = tid >> 6;
  int wr = w >> 2, wc = w & 3;

  // ---------- staging sources/dsts: 2 halves x 2 slots, 2 glds each ----------
  int g8 = (((lane & 7) ^ ((lane >> 3) & 7)) * 8);  // pre-swizzled k-group
  const unsigned short* aP[2][2];
  const unsigned short* bP[2][2];
  int aD[2][2], bD[2][2];
#pragma unroll
  for (int hf = 0; hf < 2; ++hf)
#pragma unroll
    for (int s = 0; s < 2; ++s) {
      int q0 = w * 16 + s * 8;
      // A half hf covers rows with bit6==hf: {0-63,128-191} or {64-127,192-255}
      int rbA = hf == 0 ? (q0 < 64 ? q0 : q0 + 64) : (q0 < 64 ? q0 + 64 : q0 + 128);
      int rA = rbA + (lane >> 3);
      int rr = row0 + rA; rr = rr < cntE ? rr : cntE - 1;
      if (GID == 0) {
        int tok = rows[base + rr];
        aP[hf][s] = Asrc + (size_t)tok * DIM + g8;
      } else {
        aP[hf][s] = Asrc + (size_t)(base + rr) * HID + g8;
      }
      aD[hf][s] = rbA * 64;
      int rB = hf * 128 + q0 + (lane >> 3);
      if (GID == 0) {
        int j0h = jb * 128;
        int hcol = j0h + (rB >> 5) * 16 + (rB & 15);
        int w1row = hcol + ((rB >> 4) & 1) * HID;   // +HID for b-half of swiGLU
        bP[hf][s] = Wt + ((size_t)e * 2 * HID + w1row) * DIM + g8;
      } else {
        int j0 = jb * 256;
        bP[hf][s] = Wt + ((size_t)e * DIM + (j0 + rB)) * HID + g8;
      }
      bD[hf][s] = (hf * 128 + q0) * 64;
    }

  auto stA = [&](int t, int hf) {
    if (t < NT) {
#pragma unroll
      for (int s = 0; s < 2; ++s)
        glds16(aP[hf][s] + (size_t)t * 64, smem + (t & 1) * 16384 + aD[hf][s]);
    }
  };
  auto stB = [&](int t, int hf) {
    if (t < NT) {
#pragma unroll
      for (int s = 0; s < 2; ++s)
        glds16(bP[hf][s] + (size_t)t * 64, smem + 32768 + (t & 1) * 16384 + bD[hf][s]);
    }
  };

  // ---------- ds_read offsets (elements), swizzle matches staging ----------
  int arow = wr * 128 + (lane & 15);
  int brow = wc * 64 + (lane & 15);
  int kg = lane >> 4, sx = lane & 7;
  unsigned aoffs[2] = {(unsigned)(arow * 64 + ((kg ^ sx) * 8)),
                       (unsigned)(arow * 64 + (((4 + kg) ^ sx) * 8))};
  unsigned boffs[2] = {(unsigned)(brow * 64 + ((kg ^ sx) * 8)),
                       (unsigned)(brow * 64 + (((4 + kg) ^ sx) * 8))};

  f32x4 acc[8][4];
#pragma unroll
  for (int m = 0; m < 8; ++m)
#pragma unroll
    for (int n = 0; n < 4; ++n) acc[m][n] = (f32x4){0.f, 0.f, 0.f, 0.f};

  short8 a[2][4], b[2][4];

#define MFMA_Q(MB, NB)                                                        \
  PRIO(1);                                                                    \
  _Pragma("unroll") for (int ks = 0; ks < 2; ++ks)                            \
  _Pragma("unroll") for (int m = 0; m < 4; ++m)                               \
  _Pragma("unroll") for (int n = 0; n < 2; ++n)                               \
    acc[(MB) + m][(NB) + n] = __builtin_amdgcn_mfma_f32_16x16x32_bf16(        \
        a[ks][m], b[ks][(NB) + n], acc[(MB) + m][(NB) + n], 0, 0, 0);         \
  PRIO(0)

  // ---------- prologue: A0, B0, A1 halves; land A0,B0 ----------
  stA(0, 0); stA(0, 1); stB(0, 0); stB(0, 1); stA(1, 0); stA(1, 1);
  VMW4(); FEN(); BARX(); FEN();

  for (int it = 0; it < NT / 2; ++it) {
    int T = 2 * it;
    bool notlast = (it < NT / 2 - 1);
#pragma unroll
    for (int half = 0; half < 2; ++half) {
      unsigned Ab = half ? 16384u : 0u;
      unsigned Bb = 32768u + Ab;
      int Tn = T + half;
      // ---- P0/P4: a[h0], b[v0]; stage B(Tn+1).h0 ----
#pragma unroll
      for (int ks = 0; ks < 2; ++ks) {
#pragma unroll
        for (int m = 0; m < 4; ++m)
          a[ks][m] = *(const short8*)(smem + Ab + aoffs[ks] + m * 1024);
#pragma unroll
        for (int n = 0; n < 2; ++n)
          b[ks][n] = *(const short8*)(smem + Bb + boffs[ks] + n * 1024);
      }
      stB(Tn + 1, 0);
      FEN(); BARX(); FEN();
      MFMA_Q(0, 0);
      FEN(); BARX(); FEN();
      // ---- P1/P5: b[v1]; stage B(Tn+1).h1 ----
#pragma unroll
      for (int ks = 0; ks < 2; ++ks)
#pragma unroll
        for (int n = 2; n < 4; ++n)
          b[ks][n] = *(const short8*)(smem + Bb + boffs[ks] + n * 1024);
      stB(Tn + 1, 1);
      FEN(); BARX(); FEN();
      MFMA_Q(0, 2);
      FEN(); BARX(); FEN();
      // ---- P2/P6: a[h1]; stage A(Tn+2).q0 ----
#pragma unroll
      for (int ks = 0; ks < 2; ++ks)
#pragma unroll
        for (int m = 0; m < 4; ++m)
          a[ks][m] = *(const short8*)(smem + Ab + aoffs[ks] + (4 + m) * 1024);
      stA(Tn + 2, 0);
      FEN(); BARX(); FEN();
      MFMA_Q(4, 2);
      FEN(); BARX(); FEN();
      // ---- P3/P7: stage A(Tn+2).q1; MFMA; guard-before-barrier ----
      stA(Tn + 2, 1);
      FEN(); BARX(); FEN();
      MFMA_Q(4, 0);
      if (half == 0) {
        if (notlast) { VMW4(); } else { VMW0(); }
      } else {
        VMW4();
      }
      FEN(); BARX(); FEN();
    }
  }
#undef MFMA_Q

  // ---------- epilogue ----------
  int rowl = lane >> 4, coll = lane & 15;
  if (GID == 0) {
    int j0h = jb * 128;
#pragma unroll
    for (int pair = 0; pair < 2; ++pair) {
      int hcol = j0h + (2 * wc + pair) * 16 + coll;
      float ba = bias[e * 2 * HID + hcol];
      float bb = bias[e * 2 * HID + HID + hcol];
#pragma unroll
      for (int m = 0; m < 8; ++m)
#pragma unroll
        for (int j = 0; j < 4; ++j) {
          int grow = row0 + wr * 128 + m * 16 + rowl * 4 + j;
          if (grow < cntE) {
            float av = acc[m][2 * pair][j] + ba;
            float bv = acc[m][2 * pair + 1][j] + bb;
            float hv = av / (1.f + __expf(-av)) * bv;
            hb[(size_t)(base + grow) * HID + hcol] = f2bf(hv);
          }
        }
    }
  } else {
    int j0 = jb * 256;
    float bv[4];
#pragma unroll
    for (int n = 0; n < 4; ++n) bv[n] = bias[e * DIM + j0 + wc * 64 + n * 16 + coll];
#pragma unroll
    for (int m = 0; m < 8; ++m)
#pragma unroll
      for (int j = 0; j < 4; ++j) {
        int grow = row0 + wr * 128 + m * 16 + rowl * 4 + j;
        if (grow < cntE) {
          int tok = rows[base + grow];
          float g = rowg[base + grow];
#pragma unroll
          for (int n = 0; n < 4; ++n) {
            int col = j0 + wc * 64 + n * 16 + coll;
            atomicAdd(&out[(size_t)tok * DIM + col], g * (acc[m][n][j] + bv[n]));
          }
        }
      }
  }
}

extern "C" void kernel_launch(void* const* d_in, const int* in_sizes, int n_in,
                              void* d_out, int out_size, void* d_ws, size_t ws_size,
                              hipStream_t stream) {
  (void)in_sizes; (void)n_in; (void)out_size;
  const float* x  = (const float*)d_in[0];
  const float* Wr = (const float*)d_in[1];
  const float* W1 = (const float*)d_in[2];
  const float* b1 = (const float*)d_in[3];
  const float* W2 = (const float*)d_in[4];
  const float* b2 = (const float*)d_in[5];
  float* out = (float*)d_out;
  char* ws = (char*)d_ws;

  const size_t o_xb   = 0;
  const size_t o_w1t  = o_xb   + (size_t)N_TOK * DIM * 2;
  const size_t o_w2t  = o_w1t  + (size_t)NEXP * 2 * HID * DIM * 2;
  const size_t o_hb   = o_w2t  + (size_t)NEXP * DIM * HID * 2;
  const size_t o_rows = o_hb   + (size_t)NK * HID * 2;
  const size_t o_rowg = o_rows + (size_t)NK * 4;
  const size_t o_te   = o_rowg + (size_t)NK * 4;
  const size_t o_tg   = o_te   + (size_t)NK * 4;
  const size_t o_cnt  = o_tg   + (size_t)NK * 4;
  const size_t o_offs = o_cnt  + 64;
  const size_t o_cur  = o_offs + 64;
  const size_t o_t1   = o_cur  + 64;
  const size_t need   = o_t1   + 64;
  if (ws_size < need) return;

  unsigned short* xb  = (unsigned short*)(ws + o_xb);
  unsigned short* w1t = (unsigned short*)(ws + o_w1t);
  unsigned short* w2t = (unsigned short*)(ws + o_w2t);
  unsigned short* hb  = (unsigned short*)(ws + o_hb);
  int*   rows = (int*)(ws + o_rows);
  float* rowg = (float*)(ws + o_rowg);
  int*   te   = (int*)(ws + o_te);
  float* tg   = (float*)(ws + o_tg);
  int*   cnt  = (int*)(ws + o_cnt);
  int*   offs = (int*)(ws + o_offs);
  int*   cur  = (int*)(ws + o_cur);
  int*   tl   = (int*)(ws + o_t1);

  hipMemsetAsync(out, 0, (size_t)N_TOK * DIM * sizeof(float), stream);
  hipMemsetAsync(cnt, 0, NEXP * sizeof(int), stream);

  transpose_cvt_k<<<dim3(2 * HID / 64, DIM / 64, NEXP), 256, 0, stream>>>(W1, w1t, DIM, 2 * HID);
  transpose_cvt_k<<<dim3(DIM / 64, HID / 64, NEXP), 256, 0, stream>>>(W2, w2t, HID, DIM);
  router_k<<<N_TOK / 4, 256, 0, stream>>>(x, Wr, xb, te, tg, cnt);
  scan_k<<<1, 64, 0, stream>>>(cnt, offs, cur, tl);
  scatter_k<<<N_TOK / 256, 256, 0, stream>>>(te, tg, cur, rows, rowg);
  moe_gemm8p<0><<<dim3(MAXT2, HID / 128), 512, 0, stream>>>(
      xb, w1t, b1, hb, nullptr, rows, rowg, offs, tl);
  moe_gemm8p<1><<<dim3(MAXT2, DIM / 256), 512, 0, stream>>>(
      hb, w2t, b2, nullptr, out, rows, rowg, offs, tl);
}

// Round 7
// 438.478 us; speedup vs baseline: 1.7926x; 1.5335x over previous
//
#include <hip/hip_runtime.h>

// MoE top-2/8: routed bf16-MFMA grouped GEMMs.
// R7: revert XCD swizzle (cost 7% on non-BW-bound GEMM); fuse 10 launches -> 4
// (prep = W1T || W2T || router || zero-out; sortscan = hist+scan+scatter in
// one block). GEMM schedule identical to R4 (207 us each measured).

#define N_TOK 8192
#define DIM   1024
#define HID   2048
#define NEXP  8
#define NK    (N_TOK * 2)
#define MAXT2 72    // max 256-row tiles over all experts (64 full + 8 partial)

typedef __attribute__((ext_vector_type(8))) short short8;
typedef __attribute__((ext_vector_type(4))) float f32x4;

#define BARX() __builtin_amdgcn_s_barrier()
#define FEN()  asm volatile("" ::: "memory")
#define VMW4() asm volatile("s_waitcnt vmcnt(4)" ::: "memory")
#define VMW0() asm volatile("s_waitcnt vmcnt(0)" ::: "memory")
#define PRIO(p) __builtin_amdgcn_s_setprio(p)

static __device__ __forceinline__ unsigned short f2bf(float f) {
  unsigned int u = __float_as_uint(f);
  u += 0x7fffu + ((u >> 16) & 1u);
  return (unsigned short)(u >> 16);
}

static __device__ __forceinline__ void glds16(const void* g, void* l) {
  __builtin_amdgcn_global_load_lds(
      (const __attribute__((address_space(1))) unsigned int*)g,
      (__attribute__((address_space(3))) unsigned int*)l, 16, 0, 0);
}

// ================= prep: W1^T || W2^T || router || zero(out) ================
// Grid sections (256 threads each):
//   [0,8192)      W1 [e][1024][4096] -> w1t [e][4096][1024]   (64x16 tiles x8)
//   [8192,12288)  W2 [e][2048][1024] -> w2t [e][1024][2048]   (16x32 tiles x8)
//   [12288,14336) router: logits/top2/gates + x->bf16         (4 tok/block)
//   [14336,16384) zero out[8192][1024] fp32
__device__ __forceinline__ void transpose_tile(const float* __restrict__ s,
                                               unsigned short* __restrict__ d,
                                               int R, int C, int c0, int r0,
                                               unsigned short (*tT)[68]) {
  int tid = threadIdx.x;
  int c = tid & 63, rq = tid >> 6;
#pragma unroll
  for (int q = 0; q < 4; ++q) {
    int rb = q * 16 + rq * 4;
    ushort4 v;
    v.x = f2bf(s[(size_t)(r0 + rb + 0) * C + c0 + c]);
    v.y = f2bf(s[(size_t)(r0 + rb + 1) * C + c0 + c]);
    v.z = f2bf(s[(size_t)(r0 + rb + 2) * C + c0 + c]);
    v.w = f2bf(s[(size_t)(r0 + rb + 3) * C + c0 + c]);
    *(ushort4*)&tT[c][rb] = v;
  }
  __syncthreads();
#pragma unroll
  for (int it = 0; it < 4; ++it) {
    int idx = it * 256 + tid;
    int cc = idx >> 4;
    int r4 = (idx & 15) * 4;
    *(ushort4*)(d + (size_t)(c0 + cc) * R + r0 + r4) = *(const ushort4*)&tT[cc][r4];
  }
}

__global__ __launch_bounds__(256) void prep_k(
    const float* __restrict__ x, const float* __restrict__ Wr,
    const float* __restrict__ W1, const float* __restrict__ W2,
    unsigned short* __restrict__ w1t, unsigned short* __restrict__ w2t,
    unsigned short* __restrict__ xb, int* __restrict__ te,
    float* __restrict__ tg, float* __restrict__ out) {
  __shared__ unsigned short tT[64][68];
  int bid = blockIdx.x;
  if (bid < 8192) {                       // W1 transpose
    int z = bid >> 10, rem = bid & 1023;
    int c0 = (rem & 63) * 64, r0 = (rem >> 6) * 64;
    transpose_tile(W1 + (size_t)z * DIM * 2 * HID,
                   w1t + (size_t)z * DIM * 2 * HID, DIM, 2 * HID, c0, r0, tT);
  } else if (bid < 12288) {               // W2 transpose
    int b2 = bid - 8192;
    int z = b2 >> 9, rem = b2 & 511;
    int c0 = (rem & 15) * 64, r0 = (rem >> 4) * 64;
    transpose_tile(W2 + (size_t)z * HID * DIM,
                   w2t + (size_t)z * HID * DIM, HID, DIM, c0, r0, tT);
  } else if (bid < 14336) {               // router (4 tokens, 1 wave each)
    int n = (bid - 12288) * 4 + (threadIdx.x >> 6);
    int lane = threadIdx.x & 63;
    float z[8];
#pragma unroll
    for (int e = 0; e < 8; ++e) z[e] = 0.f;
    const float* xr = x + (size_t)n * DIM;
    unsigned short* xbr = xb + (size_t)n * DIM;
#pragma unroll 4
    for (int i = 0; i < DIM / 64; ++i) {
      int d = lane + i * 64;
      float xv = xr[d];
      xbr[d] = f2bf(xv);
      float4 w0 = *(const float4*)(Wr + (size_t)d * 8);
      float4 w1 = *(const float4*)(Wr + (size_t)d * 8 + 4);
      z[0] += xv * w0.x; z[1] += xv * w0.y; z[2] += xv * w0.z; z[3] += xv * w0.w;
      z[4] += xv * w1.x; z[5] += xv * w1.y; z[6] += xv * w1.z; z[7] += xv * w1.w;
    }
    for (int off = 32; off; off >>= 1)
#pragma unroll
      for (int e = 0; e < 8; ++e) z[e] += __shfl_down(z[e], off);
    if (lane == 0) {
      int e0 = 0; float v0 = z[0];
#pragma unroll
      for (int e = 1; e < 8; ++e) if (z[e] > v0) { v0 = z[e]; e0 = e; }
      int e1 = -1; float v1 = -3.4e38f;
#pragma unroll
      for (int e = 0; e < 8; ++e) if (e != e0 && z[e] > v1) { v1 = z[e]; e1 = e; }
      float r = expf(v1 - v0);
      float s0 = 1.f / (1.f + r);
      te[n * 2] = e0; te[n * 2 + 1] = e1;
      tg[n * 2] = s0; tg[n * 2 + 1] = r * s0;
    }
  } else {                                // zero out
    int t = bid - 14336;
    float4* o4 = (float4*)out;
    int idx = t * 256 + threadIdx.x;
#pragma unroll
    for (int i = 0; i < 4; ++i) o4[idx + i * 524288] = (float4){0.f, 0.f, 0.f, 0.f};
  }
}

// ===== sortscan: one block; histogram te -> offs/tl, scatter rows/rowg ======
__global__ __launch_bounds__(1024) void sortscan_k(
    const int* __restrict__ te, const float* __restrict__ tg,
    int* __restrict__ offs, int* __restrict__ tl,
    int* __restrict__ rows, float* __restrict__ rowg) {
  __shared__ int hist[8];
  __shared__ int curs[8];
  int tid = threadIdx.x;
  if (tid < 8) hist[tid] = 0;
  __syncthreads();
  for (int i = tid; i < NK; i += 1024) atomicAdd(&hist[te[i]], 1);
  __syncthreads();
  if (tid == 0) {
    int o = 0, t = 0;
    offs[0] = 0; tl[0] = 0;
    for (int e = 0; e < NEXP; ++e) {
      curs[e] = o;
      o += hist[e];
      offs[e + 1] = o;
      t += (hist[e] + 255) >> 8;
      tl[e + 1] = t;
    }
  }
  __syncthreads();
  for (int i = tid; i < NK; i += 1024) {
    int e = te[i];
    int pos = atomicAdd(&curs[e], 1);
    rows[pos] = i >> 1;
    rowg[pos] = tg[i];
  }
}

// ================= 8-phase 256x256 grouped GEMM (per-phase interleave) ======
template <int GID>
__global__ __launch_bounds__(512, 2) void moe_gemm8p(
    const unsigned short* __restrict__ Asrc,   // xb or hb
    const unsigned short* __restrict__ Wt,     // w1t [E][4096][1024] or w2t [E][1024][2048]
    const float* __restrict__ bias,            // b1 [E][4096] or b2 [E][1024]
    unsigned short* __restrict__ hb,           // GID0 output
    float* __restrict__ out,                   // GID1 output
    const int* __restrict__ rows,
    const float* __restrict__ rowg,
    const int* __restrict__ offs,
    const int* __restrict__ tl) {
  constexpr int KD = (GID == 0) ? DIM : HID;
  constexpr int NT = KD / 64;
  // slabs (elements): A-even 0, A-odd 16384, B-even 32768, B-odd 49152
  __shared__ unsigned short smem[4 * 16384];

  int bt = blockIdx.x;
  if (bt >= tl[NEXP]) return;
  int e = 0;
  while (e < NEXP - 1 && bt >= tl[e + 1]) ++e;
  int rt = bt - tl[e];
  int base = offs[e];
  int cntE = offs[e + 1] - base;
  int row0 = rt * 256;
  int jb = blockIdx.y;

  int tid = threadIdx.x, lane = tid & 63, w = tid >> 6;
  int wr = w >> 2, wc = w & 3;

  // ---------- staging sources/dsts: 2 halves x 2 slots, 2 glds each ----------
  int g8 = (((lane & 7) ^ ((lane >> 3) & 7)) * 8);  // pre-swizzled k-group
  const unsigned short* aP[2][2];
  const unsigned short* bP[2][2];
  int aD[2][2], bD[2][2];
#pragma unroll
  for (int hf = 0; hf < 2; ++hf)
#pragma unroll
    for (int s = 0; s < 2; ++s) {
      int q0 = w * 16 + s * 8;
      // A half hf covers rows with bit6==hf: {0-63,128-191} or {64-127,192-255}
      int rbA = hf == 0 ? (q0 < 64 ? q0 : q0 + 64) : (q0 < 64 ? q0 + 64 : q0 + 128);
      int rA = rbA + (lane >> 3);
      int rr = row0 + rA; rr = rr < cntE ? rr : cntE - 1;
      if (GID == 0) {
        int tok = rows[base + rr];
        aP[hf][s] = Asrc + (size_t)tok * DIM + g8;
      } else {
        aP[hf][s] = Asrc + (size_t)(base + rr) * HID + g8;
      }
      aD[hf][s] = rbA * 64;
      int rB = hf * 128 + q0 + (lane >> 3);
      if (GID == 0) {
        int j0h = jb * 128;
        int hcol = j0h + (rB >> 5) * 16 + (rB & 15);
        int w1row = hcol + ((rB >> 4) & 1) * HID;   // +HID for b-half of swiGLU
        bP[hf][s] = Wt + ((size_t)e * 2 * HID + w1row) * DIM + g8;
      } else {
        int j0 = jb * 256;
        bP[hf][s] = Wt + ((size_t)e * DIM + (j0 + rB)) * HID + g8;
      }
      bD[hf][s] = (hf * 128 + q0) * 64;
    }

  auto stA = [&](int t, int hf) {
    if (t < NT) {
#pragma unroll
      for (int s = 0; s < 2; ++s)
        glds16(aP[hf][s] + (size_t)t * 64, smem + (t & 1) * 16384 + aD[hf][s]);
    }
  };
  auto stB = [&](int t, int hf) {
    if (t < NT) {
#pragma unroll
      for (int s = 0; s < 2; ++s)
        glds16(bP[hf][s] + (size_t)t * 64, smem + 32768 + (t & 1) * 16384 + bD[hf][s]);
    }
  };

  // ---------- ds_read offsets (elements), swizzle matches staging ----------
  int arow = wr * 128 + (lane & 15);
  int brow = wc * 64 + (lane & 15);
  int kg = lane >> 4, sx = lane & 7;
  unsigned aoffs[2] = {(unsigned)(arow * 64 + ((kg ^ sx) * 8)),
                       (unsigned)(arow * 64 + (((4 + kg) ^ sx) * 8))};
  unsigned boffs[2] = {(unsigned)(brow * 64 + ((kg ^ sx) * 8)),
                       (unsigned)(brow * 64 + (((4 + kg) ^ sx) * 8))};

  f32x4 acc[8][4];
#pragma unroll
  for (int m = 0; m < 8; ++m)
#pragma unroll
    for (int n = 0; n < 4; ++n) acc[m][n] = (f32x4){0.f, 0.f, 0.f, 0.f};

  short8 a[2][4], b[2][4];

#define MFMA_Q(MB, NB)                                                        \
  PRIO(1);                                                                    \
  _Pragma("unroll") for (int ks = 0; ks < 2; ++ks)                            \
  _Pragma("unroll") for (int m = 0; m < 4; ++m)                               \
  _Pragma("unroll") for (int n = 0; n < 2; ++n)                               \
    acc[(MB) + m][(NB) + n] = __builtin_amdgcn_mfma_f32_16x16x32_bf16(        \
        a[ks][m], b[ks][(NB) + n], acc[(MB) + m][(NB) + n], 0, 0, 0);         \
  PRIO(0)

  // ---------- prologue: A0, B0, A1 halves; land A0,B0 ----------
  stA(0, 0); stA(0, 1); stB(0, 0); stB(0, 1); stA(1, 0); stA(1, 1);
  VMW4(); FEN(); BARX(); FEN();

  for (int it = 0; it < NT / 2; ++it) {
    int T = 2 * it;
    bool notlast = (it < NT / 2 - 1);
#pragma unroll
    for (int half = 0; half < 2; ++half) {
      unsigned Ab = half ? 16384u : 0u;
      unsigned Bb = 32768u + Ab;
      int Tn = T + half;
      // ---- P0/P4: a[h0], b[v0]; stage B(Tn+1).h0 ----
#pragma unroll
      for (int ks = 0; ks < 2; ++ks) {
#pragma unroll
        for (int m = 0; m < 4; ++m)
          a[ks][m] = *(const short8*)(smem + Ab + aoffs[ks] + m * 1024);
#pragma unroll
        for (int n = 0; n < 2; ++n)
          b[ks][n] = *(const short8*)(smem + Bb + boffs[ks] + n * 1024);
      }
      stB(Tn + 1, 0);
      FEN(); BARX(); FEN();
      MFMA_Q(0, 0);
      FEN(); BARX(); FEN();
      // ---- P1/P5: b[v1]; stage B(Tn+1).h1 ----
#pragma unroll
      for (int ks = 0; ks < 2; ++ks)
#pragma unroll
        for (int n = 2; n < 4; ++n)
          b[ks][n] = *(const short8*)(smem + Bb + boffs[ks] + n * 1024);
      stB(Tn + 1, 1);
      FEN(); BARX(); FEN();
      MFMA_Q(0, 2);
      FEN(); BARX(); FEN();
      // ---- P2/P6: a[h1]; stage A(Tn+2).q0 ----
#pragma unroll
      for (int ks = 0; ks < 2; ++ks)
#pragma unroll
        for (int m = 0; m < 4; ++m)
          a[ks][m] = *(const short8*)(smem + Ab + aoffs[ks] + (4 + m) * 1024);
      stA(Tn + 2, 0);
      FEN(); BARX(); FEN();
      MFMA_Q(4, 2);
      FEN(); BARX(); FEN();
      // ---- P3/P7: stage A(Tn+2).q1; MFMA; guard-before-barrier ----
      stA(Tn + 2, 1);
      FEN(); BARX(); FEN();
      MFMA_Q(4, 0);
      if (half == 0) {
        if (notlast) { VMW4(); } else { VMW0(); }
      } else {
        VMW4();
      }
      FEN(); BARX(); FEN();
    }
  }
#undef MFMA_Q

  // ---------- epilogue ----------
  int rowl = lane >> 4, coll = lane & 15;
  if (GID == 0) {
    int j0h = jb * 128;
#pragma unroll
    for (int pair = 0; pair < 2; ++pair) {
      int hcol = j0h + (2 * wc + pair) * 16 + coll;
      float ba = bias[e * 2 * HID + hcol];
      float bb = bias[e * 2 * HID + HID + hcol];
#pragma unroll
      for (int m = 0; m < 8; ++m)
#pragma unroll
        for (int j = 0; j < 4; ++j) {
          int grow = row0 + wr * 128 + m * 16 + rowl * 4 + j;
          if (grow < cntE) {
            float av = acc[m][2 * pair][j] + ba;
            float bv = acc[m][2 * pair + 1][j] + bb;
            float hv = av / (1.f + __expf(-av)) * bv;
            hb[(size_t)(base + grow) * HID + hcol] = f2bf(hv);
          }
        }
    }
  } else {
    int j0 = jb * 256;
    float bv[4];
#pragma unroll
    for (int n = 0; n < 4; ++n) bv[n] = bias[e * DIM + j0 + wc * 64 + n * 16 + coll];
#pragma unroll
    for (int m = 0; m < 8; ++m)
#pragma unroll
      for (int j = 0; j < 4; ++j) {
        int grow = row0 + wr * 128 + m * 16 + rowl * 4 + j;
        if (grow < cntE) {
          int tok = rows[base + grow];
          float g = rowg[base + grow];
#pragma unroll
          for (int n = 0; n < 4; ++n) {
            int col = j0 + wc * 64 + n * 16 + coll;
            atomicAdd(&out[(size_t)tok * DIM + col], g * (acc[m][n][j] + bv[n]));
          }
        }
      }
  }
}

extern "C" void kernel_launch(void* const* d_in, const int* in_sizes, int n_in,
                              void* d_out, int out_size, void* d_ws, size_t ws_size,
                              hipStream_t stream) {
  (void)in_sizes; (void)n_in; (void)out_size;
  const float* x  = (const float*)d_in[0];
  const float* Wr = (const float*)d_in[1];
  const float* W1 = (const float*)d_in[2];
  const float* b1 = (const float*)d_in[3];
  const float* W2 = (const float*)d_in[4];
  const float* b2 = (const float*)d_in[5];
  float* out = (float*)d_out;
  char* ws = (char*)d_ws;

  const size_t o_xb   = 0;
  const size_t o_w1t  = o_xb   + (size_t)N_TOK * DIM * 2;
  const size_t o_w2t  = o_w1t  + (size_t)NEXP * 2 * HID * DIM * 2;
  const size_t o_hb   = o_w2t  + (size_t)NEXP * DIM * HID * 2;
  const size_t o_rows = o_hb   + (size_t)NK * HID * 2;
  const size_t o_rowg = o_rows + (size_t)NK * 4;
  const size_t o_te   = o_rowg + (size_t)NK * 4;
  const size_t o_tg   = o_te   + (size_t)NK * 4;
  const size_t o_offs = o_tg   + (size_t)NK * 4;
  const size_t o_t1   = o_offs + 64;
  const size_t need   = o_t1   + 64;
  if (ws_size < need) return;

  unsigned short* xb  = (unsigned short*)(ws + o_xb);
  unsigned short* w1t = (unsigned short*)(ws + o_w1t);
  unsigned short* w2t = (unsigned short*)(ws + o_w2t);
  unsigned short* hb  = (unsigned short*)(ws + o_hb);
  int*   rows = (int*)(ws + o_rows);
  float* rowg = (float*)(ws + o_rowg);
  int*   te   = (int*)(ws + o_te);
  float* tg   = (float*)(ws + o_tg);
  int*   offs = (int*)(ws + o_offs);
  int*   tl   = (int*)(ws + o_t1);

  prep_k<<<16384, 256, 0, stream>>>(x, Wr, W1, W2, w1t, w2t, xb, te, tg, out);
  sortscan_k<<<1, 1024, 0, stream>>>(te, tg, offs, tl, rows, rowg);
  moe_gemm8p<0><<<dim3(MAXT2, HID / 128), 512, 0, stream>>>(
      xb, w1t, b1, hb, nullptr, rows, rowg, offs, tl);
  moe_gemm8p<1><<<dim3(MAXT2, DIM / 256), 512, 0, stream>>>(
      hb, w2t, b2, nullptr, out, rows, rowg, offs, tl);
}

// Round 8
// 419.293 us; speedup vs baseline: 1.8746x; 1.0458x over previous
//
#include <hip/hip_runtime.h>

// MoE top-2/8: routed bf16-MFMA grouped GEMMs.
// R8: gemm2 tile BM=128 (524 half-cost blocks vs 264 full-cost at 1 block/CU:
// round quantization 2.0x -> ~1.18x). Same 8-phase BK=64 schedule, templated
// on BM. gemm1 (BM=256) untouched. prep/sortscan from R7.

#define N_TOK 8192
#define DIM   1024
#define HID   2048
#define NEXP  8
#define NK    (N_TOK * 2)
#define MAXT2 72    // max 256-row tiles (64 full + 8 partial)
#define MAXT1 136   // max 128-row tiles (128 full + 8 partial)

typedef __attribute__((ext_vector_type(8))) short short8;
typedef __attribute__((ext_vector_type(4))) float f32x4;

#define BARX() __builtin_amdgcn_s_barrier()
#define FEN()  asm volatile("" ::: "memory")
#define VMW4() asm volatile("s_waitcnt vmcnt(4)" ::: "memory")
#define VMW2() asm volatile("s_waitcnt vmcnt(2)" ::: "memory")
#define VMW0() asm volatile("s_waitcnt vmcnt(0)" ::: "memory")
#define PRIO(p) __builtin_amdgcn_s_setprio(p)

static __device__ __forceinline__ unsigned short f2bf(float f) {
  unsigned int u = __float_as_uint(f);
  u += 0x7fffu + ((u >> 16) & 1u);
  return (unsigned short)(u >> 16);
}

static __device__ __forceinline__ void glds16(const void* g, void* l) {
  __builtin_amdgcn_global_load_lds(
      (const __attribute__((address_space(1))) unsigned int*)g,
      (__attribute__((address_space(3))) unsigned int*)l, 16, 0, 0);
}

// ================= prep: W1^T || W2^T || router || zero(out) ================
__device__ __forceinline__ void transpose_tile(const float* __restrict__ s,
                                               unsigned short* __restrict__ d,
                                               int R, int C, int c0, int r0,
                                               unsigned short (*tT)[68]) {
  int tid = threadIdx.x;
  int c = tid & 63, rq = tid >> 6;
#pragma unroll
  for (int q = 0; q < 4; ++q) {
    int rb = q * 16 + rq * 4;
    ushort4 v;
    v.x = f2bf(s[(size_t)(r0 + rb + 0) * C + c0 + c]);
    v.y = f2bf(s[(size_t)(r0 + rb + 1) * C + c0 + c]);
    v.z = f2bf(s[(size_t)(r0 + rb + 2) * C + c0 + c]);
    v.w = f2bf(s[(size_t)(r0 + rb + 3) * C + c0 + c]);
    *(ushort4*)&tT[c][rb] = v;
  }
  __syncthreads();
#pragma unroll
  for (int it = 0; it < 4; ++it) {
    int idx = it * 256 + tid;
    int cc = idx >> 4;
    int r4 = (idx & 15) * 4;
    *(ushort4*)(d + (size_t)(c0 + cc) * R + r0 + r4) = *(const ushort4*)&tT[cc][r4];
  }
}

__global__ __launch_bounds__(256) void prep_k(
    const float* __restrict__ x, const float* __restrict__ Wr,
    const float* __restrict__ W1, const float* __restrict__ W2,
    unsigned short* __restrict__ w1t, unsigned short* __restrict__ w2t,
    unsigned short* __restrict__ xb, int* __restrict__ te,
    float* __restrict__ tg, float* __restrict__ out) {
  __shared__ unsigned short tT[64][68];
  int bid = blockIdx.x;
  if (bid < 8192) {                       // W1 transpose
    int z = bid >> 10, rem = bid & 1023;
    int c0 = (rem & 63) * 64, r0 = (rem >> 6) * 64;
    transpose_tile(W1 + (size_t)z * DIM * 2 * HID,
                   w1t + (size_t)z * DIM * 2 * HID, DIM, 2 * HID, c0, r0, tT);
  } else if (bid < 12288) {               // W2 transpose
    int b2 = bid - 8192;
    int z = b2 >> 9, rem = b2 & 511;
    int c0 = (rem & 15) * 64, r0 = (rem >> 4) * 64;
    transpose_tile(W2 + (size_t)z * HID * DIM,
                   w2t + (size_t)z * HID * DIM, HID, DIM, c0, r0, tT);
  } else if (bid < 14336) {               // router (4 tokens, 1 wave each)
    int n = (bid - 12288) * 4 + (threadIdx.x >> 6);
    int lane = threadIdx.x & 63;
    float z[8];
#pragma unroll
    for (int e = 0; e < 8; ++e) z[e] = 0.f;
    const float* xr = x + (size_t)n * DIM;
    unsigned short* xbr = xb + (size_t)n * DIM;
#pragma unroll 4
    for (int i = 0; i < DIM / 64; ++i) {
      int d = lane + i * 64;
      float xv = xr[d];
      xbr[d] = f2bf(xv);
      float4 w0 = *(const float4*)(Wr + (size_t)d * 8);
      float4 w1 = *(const float4*)(Wr + (size_t)d * 8 + 4);
      z[0] += xv * w0.x; z[1] += xv * w0.y; z[2] += xv * w0.z; z[3] += xv * w0.w;
      z[4] += xv * w1.x; z[5] += xv * w1.y; z[6] += xv * w1.z; z[7] += xv * w1.w;
    }
    for (int off = 32; off; off >>= 1)
#pragma unroll
      for (int e = 0; e < 8; ++e) z[e] += __shfl_down(z[e], off);
    if (lane == 0) {
      int e0 = 0; float v0 = z[0];
#pragma unroll
      for (int e = 1; e < 8; ++e) if (z[e] > v0) { v0 = z[e]; e0 = e; }
      int e1 = -1; float v1 = -3.4e38f;
#pragma unroll
      for (int e = 0; e < 8; ++e) if (e != e0 && z[e] > v1) { v1 = z[e]; e1 = e; }
      float r = expf(v1 - v0);
      float s0 = 1.f / (1.f + r);
      te[n * 2] = e0; te[n * 2 + 1] = e1;
      tg[n * 2] = s0; tg[n * 2 + 1] = r * s0;
    }
  } else {                                // zero out
    int t = bid - 14336;
    float4* o4 = (float4*)out;
    int idx = t * 256 + threadIdx.x;
#pragma unroll
    for (int i = 0; i < 4; ++i) o4[idx + i * 524288] = (float4){0.f, 0.f, 0.f, 0.f};
  }
}

// ===== sortscan: one block; histogram -> offs/tl256/tl128, scatter ==========
__global__ __launch_bounds__(1024) void sortscan_k(
    const int* __restrict__ te, const float* __restrict__ tg,
    int* __restrict__ offs, int* __restrict__ tl256, int* __restrict__ tl128,
    int* __restrict__ rows, float* __restrict__ rowg) {
  __shared__ int hist[8];
  __shared__ int curs[8];
  int tid = threadIdx.x;
  if (tid < 8) hist[tid] = 0;
  __syncthreads();
  for (int i = tid; i < NK; i += 1024) atomicAdd(&hist[te[i]], 1);
  __syncthreads();
  if (tid == 0) {
    int o = 0, t2 = 0, t1 = 0;
    offs[0] = 0; tl256[0] = 0; tl128[0] = 0;
    for (int e = 0; e < NEXP; ++e) {
      curs[e] = o;
      o += hist[e];
      offs[e + 1] = o;
      t2 += (hist[e] + 255) >> 8;
      tl256[e + 1] = t2;
      t1 += (hist[e] + 127) >> 7;
      tl128[e + 1] = t1;
    }
  }
  __syncthreads();
  for (int i = tid; i < NK; i += 1024) {
    int e = te[i];
    int pos = atomicAdd(&curs[e], 1);
    rows[pos] = i >> 1;
    rowg[pos] = tg[i];
  }
}

// ============ 8-phase BMx256 grouped GEMM (per-phase interleave) ============
// BM=256: MF=8 m-frags/wave, A-stage halves keyed on row bit6, guard vmcnt(4).
// BM=128: MF=4, halves keyed on bit5, guard vmcnt(2). Same race-audited
// schedule: A-half staged only after the phase that last ds_reads its rows.
template <int GID, int BM>
__global__ __launch_bounds__(512, 2) void moe_gemm8p(
    const unsigned short* __restrict__ Asrc,
    const unsigned short* __restrict__ Wt,
    const float* __restrict__ bias,
    unsigned short* __restrict__ hb,
    float* __restrict__ out,
    const int* __restrict__ rows,
    const float* __restrict__ rowg,
    const int* __restrict__ offs,
    const int* __restrict__ tl) {
  constexpr int KD = (GID == 0) ? DIM : HID;
  constexpr int NT = KD / 64;
  constexpr int MF = BM / 32;          // m-frags per wave
  constexpr int HBIT = BM / 4;         // A-half row-bit value
  constexpr int AG = BM / 128;         // glds per A-half per thread
  constexpr int ASZ = BM * 64;         // A slab elements
  // slabs (elements): A-even 0, A-odd ASZ, B-even 2*ASZ, B-odd 2*ASZ+16384
  __shared__ unsigned short smem[2 * ASZ + 2 * 16384];

  int bt = blockIdx.x;
  if (bt >= tl[NEXP]) return;
  int e = 0;
  while (e < NEXP - 1 && bt >= tl[e + 1]) ++e;
  int rt = bt - tl[e];
  int base = offs[e];
  int cntE = offs[e + 1] - base;
  int row0 = rt * BM;
  int jb = blockIdx.y;

  int tid = threadIdx.x, lane = tid & 63, w = tid >> 6;
  int wr = w >> 2, wc = w & 3;

  // ---------- staging sources/dsts ----------
  int g8 = (((lane & 7) ^ ((lane >> 3) & 7)) * 8);  // pre-swizzled k-group
  const unsigned short* aP[2][AG];
  const unsigned short* bP[2][2];
  int aD[2][AG], bD[2][2];
#pragma unroll
  for (int hf = 0; hf < 2; ++hf) {
#pragma unroll
    for (int s = 0; s < AG; ++s) {
      int q0 = w * (BM / 16) + s * 8;
      int rbA = (q0 < HBIT ? q0 : q0 + HBIT) + hf * HBIT;
      int rA = rbA + (lane >> 3);
      int rr = row0 + rA; rr = rr < cntE ? rr : cntE - 1;
      if (GID == 0) {
        int tok = rows[base + rr];
        aP[hf][s] = Asrc + (size_t)tok * DIM + g8;
      } else {
        aP[hf][s] = Asrc + (size_t)(base + rr) * HID + g8;
      }
      aD[hf][s] = rbA * 64;
    }
#pragma unroll
    for (int s = 0; s < 2; ++s) {
      int q0 = w * 16 + s * 8;
      int rB = hf * 128 + q0 + (lane >> 3);
      if (GID == 0) {
        int j0h = jb * 128;
        int hcol = j0h + (rB >> 5) * 16 + (rB & 15);
        int w1row = hcol + ((rB >> 4) & 1) * HID;   // +HID for b-half of swiGLU
        bP[hf][s] = Wt + ((size_t)e * 2 * HID + w1row) * DIM + g8;
      } else {
        int j0 = jb * 256;
        bP[hf][s] = Wt + ((size_t)e * DIM + (j0 + rB)) * HID + g8;
      }
      bD[hf][s] = (hf * 128 + q0) * 64;
    }
  }

  auto stA = [&](int t, int hf) {
    if (t < NT) {
#pragma unroll
      for (int s = 0; s < AG; ++s)
        glds16(aP[hf][s] + (size_t)t * 64, smem + (t & 1) * ASZ + aD[hf][s]);
    }
  };
  auto stB = [&](int t, int hf) {
    if (t < NT) {
#pragma unroll
      for (int s = 0; s < 2; ++s)
        glds16(bP[hf][s] + (size_t)t * 64, smem + 2 * ASZ + (t & 1) * 16384 + bD[hf][s]);
    }
  };

  // ---------- ds_read offsets (elements), swizzle matches staging ----------
  int arow = wr * (BM / 2) + (lane & 15);
  int brow = wc * 64 + (lane & 15);
  int kg = lane >> 4, sx = lane & 7;
  unsigned aoffs[2] = {(unsigned)(arow * 64 + ((kg ^ sx) * 8)),
                       (unsigned)(arow * 64 + (((4 + kg) ^ sx) * 8))};
  unsigned boffs[2] = {(unsigned)(brow * 64 + ((kg ^ sx) * 8)),
                       (unsigned)(brow * 64 + (((4 + kg) ^ sx) * 8))};

  f32x4 acc[MF][4];
#pragma unroll
  for (int m = 0; m < MF; ++m)
#pragma unroll
    for (int n = 0; n < 4; ++n) acc[m][n] = (f32x4){0.f, 0.f, 0.f, 0.f};

  short8 a[2][MF / 2], b[2][4];

#define MFMA_Q(MB, NB)                                                        \
  PRIO(1);                                                                    \
  _Pragma("unroll") for (int ks = 0; ks < 2; ++ks)                            \
  _Pragma("unroll") for (int m = 0; m < MF / 2; ++m)                          \
  _Pragma("unroll") for (int n = 0; n < 2; ++n)                               \
    acc[(MB) + m][(NB) + n] = __builtin_amdgcn_mfma_f32_16x16x32_bf16(        \
        a[ks][m], b[ks][(NB) + n], acc[(MB) + m][(NB) + n], 0, 0, 0);         \
  PRIO(0)

#define GUARD_CNT()                                                           \
  if constexpr (BM == 256) { VMW4(); } else { VMW2(); }

  // ---------- prologue: A0, B0, A1 halves; land A0,B0 ----------
  stA(0, 0); stA(0, 1); stB(0, 0); stB(0, 1); stA(1, 0); stA(1, 1);
  GUARD_CNT(); FEN(); BARX(); FEN();

  for (int it = 0; it < NT / 2; ++it) {
    int T = 2 * it;
    bool notlast = (it < NT / 2 - 1);
#pragma unroll
    for (int half = 0; half < 2; ++half) {
      unsigned Ab = half ? (unsigned)ASZ : 0u;
      unsigned Bb = 2u * ASZ + (half ? 16384u : 0u);
      int Tn = T + half;
      // ---- P0/P4: a[lo half], b[v0]; stage B(Tn+1).h0 ----
#pragma unroll
      for (int ks = 0; ks < 2; ++ks) {
#pragma unroll
        for (int m = 0; m < MF / 2; ++m)
          a[ks][m] = *(const short8*)(smem + Ab + aoffs[ks] + m * 1024);
#pragma unroll
        for (int n = 0; n < 2; ++n)
          b[ks][n] = *(const short8*)(smem + Bb + boffs[ks] + n * 1024);
      }
      stB(Tn + 1, 0);
      FEN(); BARX(); FEN();
      MFMA_Q(0, 0);
      FEN(); BARX(); FEN();
      // ---- P1/P5: b[v1]; stage B(Tn+1).h1 ----
#pragma unroll
      for (int ks = 0; ks < 2; ++ks)
#pragma unroll
        for (int n = 2; n < 4; ++n)
          b[ks][n] = *(const short8*)(smem + Bb + boffs[ks] + n * 1024);
      stB(Tn + 1, 1);
      FEN(); BARX(); FEN();
      MFMA_Q(0, 2);
      FEN(); BARX(); FEN();
      // ---- P2/P6: a[hi half]; stage A(Tn+2).q0 ----
#pragma unroll
      for (int ks = 0; ks < 2; ++ks)
#pragma unroll
        for (int m = 0; m < MF / 2; ++m)
          a[ks][m] = *(const short8*)(smem + Ab + aoffs[ks] + (MF / 2 + m) * 1024);
      stA(Tn + 2, 0);
      FEN(); BARX(); FEN();
      MFMA_Q(MF / 2, 2);
      FEN(); BARX(); FEN();
      // ---- P3/P7: stage A(Tn+2).q1; MFMA; guard-before-barrier ----
      stA(Tn + 2, 1);
      FEN(); BARX(); FEN();
      MFMA_Q(MF / 2, 0);
      if (half == 0) {
        if (notlast) { GUARD_CNT(); } else { VMW0(); }
      } else {
        GUARD_CNT();
      }
      FEN(); BARX(); FEN();
    }
  }
#undef MFMA_Q
#undef GUARD_CNT

  // ---------- epilogue ----------
  int rowl = lane >> 4, coll = lane & 15;
  if (GID == 0) {
    int j0h = jb * 128;
#pragma unroll
    for (int pair = 0; pair < 2; ++pair) {
      int hcol = j0h + (2 * wc + pair) * 16 + coll;
      float ba = bias[e * 2 * HID + hcol];
      float bb = bias[e * 2 * HID + HID + hcol];
#pragma unroll
      for (int m = 0; m < MF; ++m)
#pragma unroll
        for (int j = 0; j < 4; ++j) {
          int grow = row0 + wr * (BM / 2) + m * 16 + rowl * 4 + j;
          if (grow < cntE) {
            float av = acc[m][2 * pair][j] + ba;
            float bv = acc[m][2 * pair + 1][j] + bb;
            float hv = av / (1.f + __expf(-av)) * bv;
            hb[(size_t)(base + grow) * HID + hcol] = f2bf(hv);
          }
        }
    }
  } else {
    int j0 = jb * 256;
    float bv[4];
#pragma unroll
    for (int n = 0; n < 4; ++n) bv[n] = bias[e * DIM + j0 + wc * 64 + n * 16 + coll];
#pragma unroll
    for (int m = 0; m < MF; ++m)
#pragma unroll
      for (int j = 0; j < 4; ++j) {
        int grow = row0 + wr * (BM / 2) + m * 16 + rowl * 4 + j;
        if (grow < cntE) {
          int tok = rows[base + grow];
          float g = rowg[base + grow];
#pragma unroll
          for (int n = 0; n < 4; ++n) {
            int col = j0 + wc * 64 + n * 16 + coll;
            atomicAdd(&out[(size_t)tok * DIM + col], g * (acc[m][n][j] + bv[n]));
          }
        }
      }
  }
}

extern "C" void kernel_launch(void* const* d_in, const int* in_sizes, int n_in,
                              void* d_out, int out_size, void* d_ws, size_t ws_size,
                              hipStream_t stream) {
  (void)in_sizes; (void)n_in; (void)out_size;
  const float* x  = (const float*)d_in[0];
  const float* Wr = (const float*)d_in[1];
  const float* W1 = (const float*)d_in[2];
  const float* b1 = (const float*)d_in[3];
  const float* W2 = (const float*)d_in[4];
  const float* b2 = (const float*)d_in[5];
  float* out = (float*)d_out;
  char* ws = (char*)d_ws;

  const size_t o_xb   = 0;
  const size_t o_w1t  = o_xb   + (size_t)N_TOK * DIM * 2;
  const size_t o_w2t  = o_w1t  + (size_t)NEXP * 2 * HID * DIM * 2;
  const size_t o_hb   = o_w2t  + (size_t)NEXP * DIM * HID * 2;
  const size_t o_rows = o_hb   + (size_t)NK * HID * 2;
  const size_t o_rowg = o_rows + (size_t)NK * 4;
  const size_t o_te   = o_rowg + (size_t)NK * 4;
  const size_t o_tg   = o_te   + (size_t)NK * 4;
  const size_t o_offs = o_tg   + (size_t)NK * 4;
  const size_t o_t2   = o_offs + 64;
  const size_t o_t1   = o_t2   + 64;
  const size_t need   = o_t1   + 64;
  if (ws_size < need) return;

  unsigned short* xb  = (unsigned short*)(ws + o_xb);
  unsigned short* w1t = (unsigned short*)(ws + o_w1t);
  unsigned short* w2t = (unsigned short*)(ws + o_w2t);
  unsigned short* hb  = (unsigned short*)(ws + o_hb);
  int*   rows = (int*)(ws + o_rows);
  float* rowg = (float*)(ws + o_rowg);
  int*   te   = (int*)(ws + o_te);
  float* tg   = (float*)(ws + o_tg);
  int*   offs = (int*)(ws + o_offs);
  int*   tl256 = (int*)(ws + o_t2);
  int*   tl128 = (int*)(ws + o_t1);

  prep_k<<<16384, 256, 0, stream>>>(x, Wr, W1, W2, w1t, w2t, xb, te, tg, out);
  sortscan_k<<<1, 1024, 0, stream>>>(te, tg, offs, tl256, tl128, rows, rowg);
  moe_gemm8p<0, 256><<<dim3(MAXT2, HID / 128), 512, 0, stream>>>(
      xb, w1t, b1, hb, nullptr, rows, rowg, offs, tl256);
  moe_gemm8p<1, 128><<<dim3(MAXT1, DIM / 256), 512, 0, stream>>>(
      hb, w2t, b2, nullptr, out, rows, rowg, offs, tl128);
}